// Round 8
// baseline (166.866 us; speedup 1.0000x reference)
//
#include <hip/hip_runtime.h>

// Problem constants (from reference setup_inputs)
#define BB    2
#define CIN   64
#define NI    64
#define HIN   48
#define WIN   48
#define HO    96
#define WO    96
#define EPSN  1e-10f
#define IN_EPS 1e-5f
#define IMG   (HO*WO)     // 9216
#define NIMG  (BB*NI)     // 128
#define CS    4
#define NC    (CIN/CS)    // 16

// LDS tile (round-5 proven): 50 rows x 56 cols, input row h -> row h+1,
// input col w -> col w+4. Halo (rows 0/49, cols 0..3, 52..55) zeroed once;
// OOB taps land in the zero halo -> no masks.
#define LPH   50
#define LPW   56
#define LPAD  4
#define TILE  (LPH*LPW)

// Module-global scratch: fully rewritten every call; d_ws untouched.
__device__ float g_part[CS * NIMG * IMG];   // 18.9 MB partials
__device__ int   g_cnt[NIMG];               // arrival counters (zero-init, self-resetting)

// ---------------------------------------------------------------------------
// ONE kernel: grid (NIMG, CS) x 256. Conv (round-5 structure) writes a
// boundary-corrected partial; the LAST block per image (atomic counter)
// reduces the 4 partials, adds bias, computes stats, normalizes, writes out.
// ---------------------------------------------------------------------------
__global__ __launch_bounds__(256, 2) void fused_kernel(
        const float* __restrict__ x, const float* __restrict__ Wt,
        const float* __restrict__ bias, float* __restrict__ out) {
    const int bi = blockIdx.x, s = blockIdx.y;
    const int b = bi >> 6, i = bi & 63, c0 = s * NC;
    const int tid = threadIdx.x;
    const int ty = tid >> 4, tx = tid & 15;   // 16x16 tiles of 6x6 outputs

    __shared__ __align__(16) float sX[2][TILE];   // 22.4 KB
    __shared__ __align__(16) float sF[NC * 16];
    __shared__ float sW[NC * 16];
    __shared__ float sR[NC * 16];
    __shared__ float sFix[384];
    __shared__ float sRed[26];
    __shared__ int   sOld;

    // ---- zero both LDS tiles (halo stays zero) + in-block weight fold ----
    {
        const float4 z = make_float4(0.f, 0.f, 0.f, 0.f);
        float4* p0 = (float4*)&sX[0][0];
        for (int e = tid; e < 2 * TILE / 4; e += 256) p0[e] = z;
    }
    for (int e = tid; e < NC * 16; e += 256) {
        const int c = e >> 4, j = e & 15;
        const float* wp = Wt + ((size_t)(c0 + c) * NI + i) * 16;
        sW[e] = wp[j];
        const int py = (j >> 3) & 1, px = (j >> 2) & 1, a = (j >> 1) & 1, bb = j & 1;
        const int kh = py ? (a ? 2 : 0) : (a ? 3 : 1);
        const int kw = px ? (bb ? 2 : 0) : (bb ? 3 : 1);
        const int r0 = py ? 0 : 1, r1 = py ? 2 : 3;
        const int q0 = px ? 0 : 1, q1 = px ? 2 : 3;
        const float den = wp[r0 * 4 + q0] + wp[r0 * 4 + q1]
                        + wp[r1 * 4 + q0] + wp[r1 * 4 + q1];
        sF[e] = wp[kh * 4 + kw] / (den + EPSN);
        const int cy = j >> 2, cx = j & 3;
        const int THn[4] = {1, 2, 2, 1};
        const int THv[4][2] = {{1, 1}, {0, 2}, {1, 3}, {2, 2}};
        float den2 = 0.f;
        for (int aa = 0; aa < THn[cy]; ++aa)
            for (int bb2 = 0; bb2 < THn[cx]; ++bb2)
                den2 += wp[THv[cy][aa] * 4 + THv[cx][bb2]];
        sR[e] = 1.f / (den2 + EPSN);
    }

    // ---- staging geometry: 576 float4/channel ----
    int ldsOff[3];
#pragma unroll
    for (int k = 0; k < 3; ++k) {
        const int e = tid + 256 * k;
        const int row = e / 12, w4 = e - 12 * row;
        ldsOff[k] = (row + 1) * LPW + LPAD + 4 * w4;
    }
    const float4* xg = (const float4*)x + (size_t)(b * CIN + c0) * 576;

    // ---- boundary-pixel geometry: p0 = tid (<380), p1 = tid+256 (tid<124) ----
    int qA0[2], qA1[2], qB0[2], qB1[2], wI[2][4], clsI[2];
#pragma unroll
    for (int k = 0; k < 2; ++k) {
        const int p = tid + 256 * k;
        if (k == 1 && p >= 380) break;
        int y, xo;
        if (p < 96)       { y = 0;            xo = p; }
        else if (p < 192) { y = 95;           xo = p - 96; }
        else if (p < 286) { y = p - 192 + 1;  xo = 0; }
        else              { y = p - 286 + 1;  xo = 95; }
        const int hA = (y + 1) >> 1, hB = hA - 1;
        const int khA = (y & 1) ? 0 : 1, khB = khA + 2;
        const int wA = (xo + 1) >> 1, wB = wA - 1;
        const int kwA = (xo & 1) ? 0 : 1, kwB = kwA + 2;
        const int rA = (hA + 1) * LPW, rB = (hB + 1) * LPW;  // halo covers OOB
        qA0[k] = rA + LPAD + wA; qA1[k] = rA + LPAD + wB;
        qB0[k] = rB + LPAD + wA; qB1[k] = rB + LPAD + wB;
        wI[k][0] = khA * 4 + kwA; wI[k][1] = khA * 4 + kwB;
        wI[k][2] = khB * 4 + kwA; wI[k][3] = khB * 4 + kwB;
        const int cy = (y == 0) ? 0 : (y == 95) ? 3 : ((y & 1) ? 1 : 2);
        const int cx = (xo == 0) ? 0 : (xo == 95) ? 3 : ((xo & 1) ? 1 : 2);
        clsI[k] = cy * 4 + cx;
    }

    __syncthreads();   // zeroing + weights done

    // ---- stage channel 0 ----
    {
        float4 a0 = xg[tid], a1 = xg[tid + 256], a2;
        if (tid < 64) a2 = xg[tid + 512];
        float* d = &sX[0][0];
        *(float4*)(d + ldsOff[0]) = a0;
        *(float4*)(d + ldsOff[1]) = a1;
        if (tid < 64) *(float4*)(d + ldsOff[2]) = a2;
    }
    __syncthreads();

    float acc[6][6];
#pragma unroll
    for (int r = 0; r < 6; ++r)
#pragma unroll
        for (int j = 0; j < 6; ++j) acc[r][j] = 0.f;
    float fixAcc0 = 0.f, fixAcc1 = 0.f;

    const int patchBase = (3 * ty) * LPW + 3 * tx + (LPAD - 1);

#pragma unroll 2
    for (int c = 0; c < NC; ++c) {
        float4 a0, a1, a2;
        if (c + 1 < NC) {
            const float4* xn = xg + (size_t)(c + 1) * 576;
            a0 = xn[tid]; a1 = xn[tid + 256];
            if (tid < 64) a2 = xn[tid + 512];
        }

        const float* __restrict__ xs = &sX[c & 1][0];

        float g[16];
        {
            const float4* gf = (const float4*)&sF[c * 16];
#pragma unroll
            for (int q = 0; q < 4; ++q) {
                const float4 t = gf[q];
                g[4 * q] = t.x; g[4 * q + 1] = t.y;
                g[4 * q + 2] = t.z; g[4 * q + 3] = t.w;
            }
        }

        float xv[5][5];
#pragma unroll
        for (int rr = 0; rr < 5; ++rr)
#pragma unroll
            for (int cc = 0; cc < 5; ++cc)
                xv[rr][cc] = xs[patchBase + rr * LPW + cc];

#pragma unroll
        for (int r = 0; r < 6; ++r) {
            const int rhi = (r + 3) >> 1, rlo = rhi - 1, py = r & 1;
#pragma unroll
            for (int j = 0; j < 6; ++j) {
                const int chi = (j + 3) >> 1, clo = chi - 1, px = j & 1;
                const float* gg = &g[py * 8 + px * 4];
                acc[r][j] += xv[rhi][chi] * gg[0] + xv[rhi][clo] * gg[1]
                           + xv[rlo][chi] * gg[2] + xv[rlo][clo] * gg[3];
            }
        }

        {
            const float* wc = &sW[c * 16];
            const float num0 = xs[qA0[0]] * wc[wI[0][0]] + xs[qA1[0]] * wc[wI[0][1]]
                             + xs[qB0[0]] * wc[wI[0][2]] + xs[qB1[0]] * wc[wI[0][3]];
            fixAcc0 += num0 * sR[c * 16 + clsI[0]];
            if (tid < 124) {
                const float num1 = xs[qA0[1]] * wc[wI[1][0]] + xs[qA1[1]] * wc[wI[1][1]]
                                 + xs[qB0[1]] * wc[wI[1][2]] + xs[qB1[1]] * wc[wI[1][3]];
                fixAcc1 += num1 * sR[c * 16 + clsI[1]];
            }
        }

        if (c + 1 < NC) {
            float* d = &sX[(c + 1) & 1][0];
            *(float4*)(d + ldsOff[0]) = a0;
            *(float4*)(d + ldsOff[1]) = a1;
            if (tid < 64) *(float4*)(d + ldsOff[2]) = a2;
        }
        __syncthreads();
    }

    // publish boundary sums; owners replace their boundary pixels
    sFix[tid] = fixAcc0;
    if (tid < 124) sFix[tid + 256] = fixAcc1;
    __syncthreads();

#pragma unroll
    for (int r = 0; r < 6; ++r)
#pragma unroll
        for (int j = 0; j < 6; ++j) {
            const int y = 6 * ty + r, xo = 6 * tx + j;
            if (y == 0)        acc[r][j] = sFix[xo];
            else if (y == 95)  acc[r][j] = sFix[96 + xo];
            else if (xo == 0)  acc[r][j] = sFix[192 + y - 1];
            else if (xo == 95) acc[r][j] = sFix[286 + y - 1];
        }

    // ---- write partial ----
    {
        float* pp = g_part + ((size_t)s * NIMG + bi) * IMG + (6 * ty) * WO + 6 * tx;
#pragma unroll
        for (int r = 0; r < 6; ++r)
#pragma unroll
            for (int jj = 0; jj < 3; ++jj) {
                float2 v;
                v.x = acc[r][2 * jj];
                v.y = acc[r][2 * jj + 1];
                *(float2*)(pp + r * WO + 2 * jj) = v;
            }
    }

    // ---- arrival: last block per image does the epilogue ----
    __threadfence();            // make this block's partial visible device-wide
    __syncthreads();
    if (tid == 0) sOld = atomicAdd(&g_cnt[bi], 1);
    __syncthreads();
    if (sOld != CS - 1) return;
    __threadfence();            // acquire: see all partials

    const float bv = bias[i];
    const float4* pb = (const float4*)g_part;
    float4 v[9];
    float s1 = 0.f, s2 = 0.f;
#pragma unroll
    for (int k = 0; k < 9; ++k) {
        const int pix4 = k * 256 + tid;
        float4 t = pb[(size_t)bi * 2304 + pix4];
#pragma unroll
        for (int sp = 1; sp < CS; ++sp) {
            const float4 q = pb[((size_t)sp * NIMG + bi) * 2304 + pix4];
            t.x += q.x; t.y += q.y; t.z += q.z; t.w += q.w;
        }
        t.x += bv; t.y += bv; t.z += bv; t.w += bv;
        v[k] = t;
        s1 += t.x + t.y + t.z + t.w;
        s2 += t.x * t.x + t.y * t.y + t.z * t.z + t.w * t.w;
    }

#pragma unroll
    for (int off = 32; off > 0; off >>= 1) {
        s1 += __shfl_down(s1, off, 64);
        s2 += __shfl_down(s2, off, 64);
    }
    const int w = tid >> 6;
    if ((tid & 63) == 0) { sRed[w] = s1; sRed[4 + w] = s2; }
    __syncthreads();
    if (tid == 0) {
        const float t1 = sRed[0] + sRed[1] + sRed[2] + sRed[3];
        const float t2 = sRed[4] + sRed[5] + sRed[6] + sRed[7];
        const float mean = t1 * (1.f / 9216.f);
        const float m2 = t2 * (1.f / 9216.f);
        sRed[24] = mean;
        sRed[25] = rsqrtf(m2 - mean * mean + IN_EPS);
        g_cnt[bi] = 0;          // self-reset for the next (graph-replayed) call
    }
    __syncthreads();
    const float mean = sRed[24], inv = sRed[25];

    float4* ob = (float4*)out + (size_t)bi * 2304;
#pragma unroll
    for (int k = 0; k < 9; ++k) {
        const int pix4 = k * 256 + tid;
        float4 t = v[k];
        t.x = (t.x - mean) * inv; t.y = (t.y - mean) * inv;
        t.z = (t.z - mean) * inv; t.w = (t.w - mean) * inv;
        ob[pix4] = t;
    }
}

extern "C" void kernel_launch(void* const* d_in, const int* in_sizes, int n_in,
                              void* d_out, int out_size, void* d_ws, size_t ws_size,
                              hipStream_t stream) {
    const float* x    = (const float*)d_in[0];
    const float* Wt   = (const float*)d_in[1];
    const float* bias = (const float*)d_in[2];
    float* out = (float*)d_out;
    (void)d_ws; (void)ws_size;

    fused_kernel<<<dim3(NIMG, CS), 256, 0, stream>>>(x, Wt, bias, out);
}

// Round 9
// 87.039 us; speedup vs baseline: 1.9171x; 1.9171x over previous
//
#include <hip/hip_runtime.h>
#include <hip/hip_fp16.h>

// Problem constants (from reference setup_inputs)
#define BB    2
#define CIN   64
#define NI    64
#define HIN   48
#define WIN   48
#define HO    96
#define WO    96
#define EPSN  1e-10f
#define IN_EPS 1e-5f
#define IMG   (HO*WO)     // 9216
#define NIMG  (BB*NI)     // 128
#define CS    4
#define NC    (CIN/CS)    // 16

// LDS tile: 50 rows x 52 cols. Input row h -> LDS row h+1 (rows 0 and 49 are
// zero guards). Input col w -> LDS col w (col 48 is a zero guard; 49..51 pad).
// OOB taps are REDIRECTED into guard cells -> no per-element masks anywhere.
#define TW    52
#define TROWS 50
#define TILE  (TROWS*TW)   // 2600 floats

// Module-global scratch (d_ws untouched). fp16 partials: 9.4 MB.
__device__ __align__(16) __half2 g_part[CS * NIMG * (IMG / 2)];

// ---------------------------------------------------------------------------
// conv: grid (NIMG, CS) x 192 threads. Block (bi,s): full 96x96 image for
// out-channel i, batch b over channels [s*NC,(s+1)*NC), boundary-corrected,
// written as fp16 pairs to g_part[s][bi]. Thread tile 6 rows x 8 cols.
// Weights folded in-block into LDS (round-5 proven); x staged per channel
// into the guarded LDS tile, double-buffered; patch read b32+b128+b32.
// ---------------------------------------------------------------------------
__global__ __launch_bounds__(192, 2) void conv_kernel(
        const float* __restrict__ x, const float* __restrict__ Wt,
        float* __restrict__ unused) {
    const int bi = blockIdx.x, s = blockIdx.y;
    const int b = bi >> 6, i = bi & 63, c0 = s * NC;
    const int tid = threadIdx.x;
    const int ty = tid / 12, tx = tid - 12 * ty;   // 16 x 12 thread tiles

    __shared__ __align__(16) float sX[2][TILE];    // 20.8 KB
    __shared__ __align__(16) float sF[NC * 16];    // folded interior weights
    __shared__ float sW[NC * 16];                  // raw weights (boundary)
    __shared__ float sR[NC * 16];                  // class reciprocals
    __shared__ float sFix[384];

    // ---- zero guard cells (disjoint from staged interior) ----
    {
        const float4 z = make_float4(0.f, 0.f, 0.f, 0.f);
        for (int e = tid; e < 2 * TROWS; e += 192) {
            const int q = e / TROWS, row = e - q * TROWS;
            float* rp = &sX[q][row * TW];
            if (row == 0 || row == TROWS - 1) {
#pragma unroll
                for (int k = 0; k < TW; k += 4) *(float4*)(rp + k) = z;
            } else {
                *(float4*)(rp + 48) = z;
            }
        }
    }

    // ---- in-block weight fold ----
    for (int e = tid; e < NC * 16; e += 192) {
        const int c = e >> 4, j = e & 15;
        const float* wp = Wt + ((size_t)(c0 + c) * NI + i) * 16;
        sW[e] = wp[j];
        const int py = (j >> 3) & 1, px = (j >> 2) & 1, a = (j >> 1) & 1, bb = j & 1;
        const int kh = py ? (a ? 2 : 0) : (a ? 3 : 1);
        const int kw = px ? (bb ? 2 : 0) : (bb ? 3 : 1);
        const int r0 = py ? 0 : 1, r1 = py ? 2 : 3;
        const int q0 = px ? 0 : 1, q1 = px ? 2 : 3;
        const float den = wp[r0 * 4 + q0] + wp[r0 * 4 + q1]
                        + wp[r1 * 4 + q0] + wp[r1 * 4 + q1];
        sF[e] = wp[kh * 4 + kw] / (den + EPSN);
        const int cy = j >> 2, cx = j & 3;
        const int THn[4] = {1, 2, 2, 1};
        const int THv[4][2] = {{1, 1}, {0, 2}, {1, 3}, {2, 2}};
        float den2 = 0.f;
        for (int aa = 0; aa < THn[cy]; ++aa)
            for (int bb2 = 0; bb2 < THn[cx]; ++bb2)
                den2 += wp[THv[cy][aa] * 4 + THv[cx][bb2]];
        sR[e] = 1.f / (den2 + EPSN);
    }

    // ---- staging geometry: 576 float4/channel, 3 per thread ----
    int ldsOff[3];
#pragma unroll
    for (int k = 0; k < 3; ++k) {
        const int e = tid + 192 * k;
        const int row = e / 12, c4 = e - 12 * row;
        ldsOff[k] = (row + 1) * TW + 4 * c4;
    }
    const float4* xg = (const float4*)x + (size_t)(b * CIN + c0) * 576;

    // ---- patch geometry ----
    const int rowBase = 3 * ty;
    const int cMain = 4 * tx;
    const int cE0 = (tx == 0) ? 48 : 4 * tx - 1;
    const int cE5 = (tx == 11) ? 48 : 4 * tx + 4;

    // ---- boundary-pixel geometry: p0 = tid, p1 = tid + 192 (tid < 188) ----
    int qA0[2], qA1[2], qB0[2], qB1[2], wI[2][4], clsI[2];
#pragma unroll
    for (int k = 0; k < 2; ++k) {
        const int p = tid + 192 * k;
        if (k == 1 && p >= 380) break;
        int y, xo;
        if (p < 96)       { y = 0;            xo = p; }
        else if (p < 192) { y = 95;           xo = p - 96; }
        else if (p < 286) { y = p - 192 + 1;  xo = 0; }
        else              { y = p - 286 + 1;  xo = 95; }
        const int hA = (y + 1) >> 1, hB = hA - 1;
        const int khA = (y & 1) ? 0 : 1, khB = khA + 2;
        const int wA = (xo + 1) >> 1, wB = wA - 1;
        const int kwA = (xo & 1) ? 0 : 1, kwB = kwA + 2;
        const int colA = wA;                  // wA==48 (xo==95) -> guard col
        const int colB = (wB < 0) ? 48 : wB;  // wB==-1 (xo==0)  -> guard col
        const int rA = (hA + 1) * TW, rB = (hB + 1) * TW;  // guards cover OOB rows
        qA0[k] = rA + colA; qA1[k] = rA + colB;
        qB0[k] = rB + colA; qB1[k] = rB + colB;
        wI[k][0] = khA * 4 + kwA; wI[k][1] = khA * 4 + kwB;
        wI[k][2] = khB * 4 + kwA; wI[k][3] = khB * 4 + kwB;
        const int cy = (y == 0) ? 0 : (y == 95) ? 3 : ((y & 1) ? 1 : 2);
        const int cx = (xo == 0) ? 0 : (xo == 95) ? 3 : ((xo & 1) ? 1 : 2);
        clsI[k] = cy * 4 + cx;
    }

    __syncthreads();   // guards zeroed, weights folded

    // ---- stage channel 0 ----
    {
        const float4 a0 = xg[tid], a1 = xg[tid + 192], a2 = xg[tid + 384];
        float* d = &sX[0][0];
        *(float4*)(d + ldsOff[0]) = a0;
        *(float4*)(d + ldsOff[1]) = a1;
        *(float4*)(d + ldsOff[2]) = a2;
    }
    __syncthreads();

    float acc[6][8];
#pragma unroll
    for (int r = 0; r < 6; ++r)
#pragma unroll
        for (int j = 0; j < 8; ++j) acc[r][j] = 0.f;
    float fixAcc0 = 0.f, fixAcc1 = 0.f;

#pragma unroll 2
    for (int c = 0; c < NC; ++c) {
        // prefetch next channel
        float4 a0, a1, a2;
        if (c + 1 < NC) {
            const float4* xn = xg + (size_t)(c + 1) * 576;
            a0 = xn[tid]; a1 = xn[tid + 192]; a2 = xn[tid + 384];
        }

        // folded weights from LDS (b128 x4)
        float g[16];
        {
            const float4* gf = (const float4*)&sF[c * 16];
#pragma unroll
            for (int q = 0; q < 4; ++q) {
                const float4 t = gf[q];
                g[4 * q] = t.x; g[4 * q + 1] = t.y;
                g[4 * q + 2] = t.z; g[4 * q + 3] = t.w;
            }
        }

        const float* __restrict__ xs = &sX[c & 1][0];

        // patch: 5 rows x (b32 + b128 + b32)
        float xv[5][6];
#pragma unroll
        for (int pr = 0; pr < 5; ++pr) {
            const int ro = (rowBase + pr) * TW;
            xv[pr][0] = xs[ro + cE0];
            const float4 m = *(const float4*)(xs + ro + cMain);
            xv[pr][1] = m.x; xv[pr][2] = m.y; xv[pr][3] = m.z; xv[pr][4] = m.w;
            xv[pr][5] = xs[ro + cE5];
        }

#pragma unroll
        for (int r = 0; r < 6; ++r) {
            const int prA = ((r + 1) >> 1) + 1, prB = prA - 1;
            const int py = r & 1;
#pragma unroll
            for (int j = 0; j < 8; ++j) {
                const int pcA = ((j + 1) >> 1) + 1, pcB = pcA - 1;
                const int px = j & 1;
                const float* gg = &g[py * 8 + px * 4];
                acc[r][j] += xv[prA][pcA] * gg[0] + xv[prA][pcB] * gg[1]
                           + xv[prB][pcA] * gg[2] + xv[prB][pcB] * gg[3];
            }
        }

        // boundary contribution of this channel
        {
            const float* wc = &sW[c * 16];
            const float num0 = xs[qA0[0]] * wc[wI[0][0]] + xs[qA1[0]] * wc[wI[0][1]]
                             + xs[qB0[0]] * wc[wI[0][2]] + xs[qB1[0]] * wc[wI[0][3]];
            fixAcc0 += num0 * sR[c * 16 + clsI[0]];
            if (tid < 188) {
                const float num1 = xs[qA0[1]] * wc[wI[1][0]] + xs[qA1[1]] * wc[wI[1][1]]
                                 + xs[qB0[1]] * wc[wI[1][2]] + xs[qB1[1]] * wc[wI[1][3]];
                fixAcc1 += num1 * sR[c * 16 + clsI[1]];
            }
        }

        // commit prefetched channel to the other buffer
        if (c + 1 < NC) {
            float* d = &sX[(c + 1) & 1][0];
            *(float4*)(d + ldsOff[0]) = a0;
            *(float4*)(d + ldsOff[1]) = a1;
            *(float4*)(d + ldsOff[2]) = a2;
        }
        __syncthreads();
    }

    // publish boundary sums; owners replace their boundary pixels
    sFix[tid] = fixAcc0;
    if (tid < 188) sFix[192 + tid] = fixAcc1;
    __syncthreads();

#pragma unroll
    for (int r = 0; r < 6; ++r)
#pragma unroll
        for (int j = 0; j < 8; ++j) {
            const int y = 6 * ty + r, xo = 8 * tx + j;
            if (y == 0)        acc[r][j] = sFix[xo];
            else if (y == 95)  acc[r][j] = sFix[96 + xo];
            else if (xo == 0)  acc[r][j] = sFix[192 + y - 1];
            else if (xo == 95) acc[r][j] = sFix[286 + y - 1];
        }

    // ---- write fp16 partial: 8 floats -> 4 half2 -> one 16B store per row ----
    {
        __half2* pp = g_part + ((size_t)s * NIMG + bi) * (IMG / 2)
                    + (6 * ty) * (WO / 2) + 4 * tx;
#pragma unroll
        for (int r = 0; r < 6; ++r) {
            __half2 h[4];
#pragma unroll
            for (int q = 0; q < 4; ++q)
                h[q] = __floats2half2_rn(acc[r][2 * q], acc[r][2 * q + 1]);
            *(float4*)(pp + r * (WO / 2)) = *(float4*)h;
        }
    }
}

// ---------------------------------------------------------------------------
// epilogue: grid NIMG x 768 threads (12 waves). Sum CS fp16 partials,
// +bias (fp32, exact), block-wide stats, normalize, write out.
// ---------------------------------------------------------------------------
__global__ __launch_bounds__(768) void epilogue_kernel(
        const float* __restrict__ bias, float* __restrict__ out) {
    const int bi = blockIdx.x;
    const int tid = threadIdx.x;
    const float bv = bias[bi & 63];
    const __half2* pb = g_part + (size_t)bi * (IMG / 2);
    const size_t stride2 = (size_t)NIMG * (IMG / 2);

    float4 v[3];
    float s1 = 0.f, s2 = 0.f;
#pragma unroll
    for (int k = 0; k < 3; ++k) {
        const int idx2 = (k * 768 + tid) * 2;   // half2 index (4 px)
        float ax = 0.f, ay = 0.f, az = 0.f, aw = 0.f;
#pragma unroll
        for (int sp = 0; sp < CS; ++sp) {
            const float2 raw = *(const float2*)(pb + sp * stride2 + idx2);
            const __half2 h0 = ((const __half2*)&raw)[0];
            const __half2 h1 = ((const __half2*)&raw)[1];
            const float2 f0 = __half22float2(h0);
            const float2 f1 = __half22float2(h1);
            ax += f0.x; ay += f0.y; az += f1.x; aw += f1.y;
        }
        float4 t;
        t.x = ax + bv; t.y = ay + bv; t.z = az + bv; t.w = aw + bv;
        v[k] = t;
        s1 += t.x + t.y + t.z + t.w;
        s2 += t.x * t.x + t.y * t.y + t.z * t.z + t.w * t.w;
    }

    __shared__ float red[24];
    __shared__ float stat[2];
#pragma unroll
    for (int off = 32; off > 0; off >>= 1) {
        s1 += __shfl_down(s1, off, 64);
        s2 += __shfl_down(s2, off, 64);
    }
    const int w = tid >> 6;
    if ((tid & 63) == 0) { red[w] = s1; red[12 + w] = s2; }
    __syncthreads();
    if (tid == 0) {
        float t1 = 0.f, t2 = 0.f;
#pragma unroll
        for (int k = 0; k < 12; ++k) { t1 += red[k]; t2 += red[12 + k]; }
        const float mean = t1 * (1.f / 9216.f);
        const float m2 = t2 * (1.f / 9216.f);
        stat[0] = mean;
        stat[1] = rsqrtf(m2 - mean * mean + IN_EPS);
    }
    __syncthreads();
    const float mean = stat[0], inv = stat[1];

    float4* ob = (float4*)out + (size_t)bi * (IMG / 4);
#pragma unroll
    for (int k = 0; k < 3; ++k) {
        const int idx = k * 768 + tid;
        float4 t = v[k];
        t.x = (t.x - mean) * inv; t.y = (t.y - mean) * inv;
        t.z = (t.z - mean) * inv; t.w = (t.w - mean) * inv;
        ob[idx] = t;
    }
}

extern "C" void kernel_launch(void* const* d_in, const int* in_sizes, int n_in,
                              void* d_out, int out_size, void* d_ws, size_t ws_size,
                              hipStream_t stream) {
    const float* x    = (const float*)d_in[0];
    const float* Wt   = (const float*)d_in[1];
    const float* bias = (const float*)d_in[2];
    float* out = (float*)d_out;
    (void)d_ws; (void)ws_size;

    conv_kernel<<<dim3(NIMG, CS), 192, 0, stream>>>(x, Wt, nullptr);
    epilogue_kernel<<<NIMG, 768, 0, stream>>>(bias, out);
}